// Round 1
// baseline (114.250 us; speedup 1.0000x reference)
//
#include <hip/hip_runtime.h>
#include <math.h>

// Persistent scratch for the three 8x8 complex ansatz-layer matrices.
// Recomputed from theta on EVERY kernel_launch call (no stale-state reliance).
// Layout (float2 units): [layer][row][col], layer*64 + row*8 + col.
__device__ float2 g_layers[192];

// ---------------------------------------------------------------------------
// Prep: 24 threads, thread (l,c) evolves basis column c through ansatz layer l.
// Qubit i lives at bit (2-i) of the flattened index (q0*4 + q1*2 + q2).
// ---------------------------------------------------------------------------
__global__ void qb_prep(const float* __restrict__ theta)
{
    const int tid = threadIdx.x;
    if (tid >= 24) return;
    const int l = tid >> 3;   // layer 0..2
    const int c = tid & 7;    // column 0..7

    float re[8], im[8];
#pragma unroll
    for (int k = 0; k < 8; ++k) { re[k] = (k == c) ? 1.f : 0.f; im[k] = 0.f; }

#pragma unroll
    for (int q = 0; q < 3; ++q) {
        const int p  = 2 - q;       // bit position for qubit q
        const int st = 1 << p;
        const float a0 = theta[l * 9 + q * 3 + 0];
        const float a1 = theta[l * 9 + q * 3 + 1];
        const float a2 = theta[l * 9 + q * 3 + 2];
        float sz, cz, sx, cx, sz2, cz2;
        __sincosf(0.5f * a0, &sz,  &cz);
        __sincosf(0.5f * a1, &sx,  &cx);
        __sincosf(0.5f * a2, &sz2, &cz2);

        // RZ(a0): bit==0 -> *(cz - i sz); bit==1 -> *(cz + i sz)
#pragma unroll
        for (int k = 0; k < 8; ++k) {
            const float s = ((k >> p) & 1) ? sz : -sz;
            const float r0 = re[k] * cz - im[k] * s;
            const float i0 = re[k] * s  + im[k] * cz;
            re[k] = r0; im[k] = i0;
        }
        // RX(a1): [[c, -is],[-is, c]] on pairs (k, k+st)
#pragma unroll
        for (int k = 0; k < 8; ++k) {
            if ((k >> p) & 1) continue;
            const int k1 = k + st;
            const float r0 =  cx * re[k]  + sx * im[k1];
            const float i0 =  cx * im[k]  - sx * re[k1];
            const float r1 =  sx * im[k]  + cx * re[k1];
            const float i1 = -sx * re[k]  + cx * im[k1];
            re[k] = r0; im[k] = i0; re[k1] = r1; im[k1] = i1;
        }
        // RZ(a2)
#pragma unroll
        for (int k = 0; k < 8; ++k) {
            const float s = ((k >> p) & 1) ? sz2 : -sz2;
            const float r0 = re[k] * cz2 - im[k] * s;
            const float i0 = re[k] * s   + im[k] * cz2;
            re[k] = r0; im[k] = i0;
        }
    }

    // CNOT(0,1): ctrl bit2, swap bit1 pairs: (4,6),(5,7)
    // CNOT(1,2): ctrl bit1, swap bit0 pairs: (2,3),(6,7)
    // CNOT(2,0): ctrl bit0, swap bit2 pairs: (1,5),(3,7)
#define SWP(a, b) { float tr = re[a]; re[a] = re[b]; re[b] = tr; \
                    float ti = im[a]; im[a] = im[b]; im[b] = ti; }
    SWP(4, 6); SWP(5, 7);
    SWP(2, 3); SWP(6, 7);
    SWP(1, 5); SWP(3, 7);
#undef SWP

#pragma unroll
    for (int r = 0; r < 8; ++r)
        g_layers[l * 64 + r * 8 + c] = make_float2(re[r], im[r]);
}

// ---------------------------------------------------------------------------
// Main: one thread per sample.
// ---------------------------------------------------------------------------

// Real RY butterfly on bit with stride ST: (a,b) -> (c*a - s*b, s*a + c*b)
template <int ST>
__device__ __forceinline__ void rotF(float c, float s, float (&vr)[8], float (&vi)[8])
{
#pragma unroll
    for (int k = 0; k < 8; ++k) {
        if (k & ST) continue;
        const int k1 = k + ST;
        const float ar = vr[k],  ai = vi[k];
        const float br = vr[k1], bi = vi[k1];
        vr[k]  = c * ar - s * br;  vi[k]  = c * ai - s * bi;
        vr[k1] = s * ar + c * br;  vi[k1] = s * ai + c * bi;
    }
}

__global__ __launch_bounds__(256) void qb_main(const float* __restrict__ t,
                                               float* __restrict__ out, int n)
{
    // Stage the three matrices (as float4 = 2 complex entries) in LDS.
    __shared__ float4 U[96];
    const float4* gsrc = reinterpret_cast<const float4*>(g_layers);
    for (int i = threadIdx.x; i < 96; i += 256) U[i] = gsrc[i];
    __syncthreads();

    const int b = blockIdx.x * 256 + threadIdx.x;
    if (b >= n) return;

    const float th = 1.5707963267948966f * t[b];  // theta = pi*t/2
    float s1, c1;
    __sincosf(th, &s1, &c1);
    const float c2 = c1 * c1 - s1 * s1, s2 = 2.f * s1 * c1;        // 2*theta
    const float c3 = c2 * c1 - s2 * s1, s3 = s2 * c1 + c2 * s1;    // 3*theta

    // w = column 0 of layer0 (= L0 |000>)
    float wr[8], wi[8];
#pragma unroll
    for (int r = 0; r < 8; ++r) { const float4 u = U[r * 4]; wr[r] = u.x; wi[r] = u.y; }

    // w = F(t) w : qubit0 (freq 1) on bit2, qubit1 (freq 2) on bit1, qubit2 (freq 3) on bit0
    rotF<4>(c1, s1, wr, wi);
    rotF<2>(c2, s2, wr, wi);
    rotF<1>(c3, s3, wr, wi);

    // x = L1 * w   (L1 at float4 base 32)
    float xr[8], xi[8];
#pragma unroll
    for (int r = 0; r < 8; ++r) {
        float zr = 0.f, zi = 0.f;
#pragma unroll
        for (int c4 = 0; c4 < 4; ++c4) {
            const float4 u = U[32 + r * 4 + c4];
            const int cc = 2 * c4;
            zr += u.x * wr[cc]     - u.y * wi[cc];
            zi += u.x * wi[cc]     + u.y * wr[cc];
            zr += u.z * wr[cc + 1] - u.w * wi[cc + 1];
            zi += u.z * wi[cc + 1] + u.w * wr[cc + 1];
        }
        xr[r] = zr; xi[r] = zi;
    }

    // x = F(t) x
    rotF<4>(c1, s1, xr, xi);
    rotF<2>(c2, s2, xr, xi);
    rotF<1>(c3, s3, xr, xi);

    // z = L2 * x (L2 at float4 base 64); acc = sum_k sign_k |z_k|^2
    float acc = 0.f;
#pragma unroll
    for (int r = 0; r < 8; ++r) {
        float zr = 0.f, zi = 0.f;
#pragma unroll
        for (int c4 = 0; c4 < 4; ++c4) {
            const float4 u = U[64 + r * 4 + c4];
            const int cc = 2 * c4;
            zr += u.x * xr[cc]     - u.y * xi[cc];
            zi += u.x * xi[cc]     + u.y * xr[cc];
            zr += u.z * xr[cc + 1] - u.w * xi[cc + 1];
            zi += u.z * xi[cc + 1] + u.w * xr[cc + 1];
        }
        const float m = zr * zr + zi * zi;
        acc += (r < 4) ? m : -m;
    }

    out[b] = acc;
}

extern "C" void kernel_launch(void* const* d_in, const int* in_sizes, int n_in,
                              void* d_out, int out_size, void* d_ws, size_t ws_size,
                              hipStream_t stream)
{
    const float* t     = (const float*)d_in[0];
    const float* theta = (const float*)d_in[1];
    float* out         = (float*)d_out;
    const int n = in_sizes[0];

    qb_prep<<<1, 64, 0, stream>>>(theta);
    const int blocks = (n + 255) / 256;
    qb_main<<<blocks, 256, 0, stream>>>(t, out, n);
}

// Round 2
// 79.450 us; speedup vs baseline: 1.4380x; 1.4380x over previous
//
#include <hip/hip_runtime.h>
#include <math.h>

#ifndef M_PI
#define M_PI 3.14159265358979323846
#endif

// 25 harmonics (k=0..24) of out(theta), theta = pi*t/2:
// g_coef[2k] = a_k (cos), g_coef[2k+1] = b_k (sin). [50],[51] zeroed.
__device__ float g_coef[52];

__device__ __forceinline__ float rfl(float x)
{
    return __int_as_float(__builtin_amdgcn_readfirstlane(__float_as_int(x)));
}

// Real RY butterfly on bit with stride ST: (a,b) -> (c*a - s*b, s*a + c*b)
template <int ST>
__device__ __forceinline__ void rotF(float c, float s, float (&vr)[8], float (&vi)[8])
{
#pragma unroll
    for (int k = 0; k < 8; ++k) {
        if (k & ST) continue;
        const int k1 = k + ST;
        const float ar = vr[k],  ai = vi[k];
        const float br = vr[k1], bi = vi[k1];
        vr[k]  = c * ar - s * br;  vi[k]  = c * ai - s * bi;
        vr[k1] = s * ar + c * br;  vi[k1] = s * ai + c * bi;
    }
}

// ---------------------------------------------------------------------------
// Prep (1 block, 64 threads):
//  1) threads 0..23 build the three 8x8 ansatz-layer matrices into LDS
//  2) every thread j evaluates the circuit at theta_j = 2*pi*j/64
//  3) threads 0..24 do the 64-point real DFT -> a_k, b_k (exact: deg 24 < 32)
// ---------------------------------------------------------------------------
__global__ void qb_prep(const float* __restrict__ theta)
{
    __shared__ float2 sU[192];   // [layer][row][col]
    __shared__ float  sOut[64];
    const int tid = threadIdx.x;

    if (tid < 24) {
        const int l = tid >> 3;   // layer
        const int c = tid & 7;    // column

        float re[8], im[8];
#pragma unroll
        for (int k = 0; k < 8; ++k) { re[k] = (k == c) ? 1.f : 0.f; im[k] = 0.f; }

#pragma unroll
        for (int q = 0; q < 3; ++q) {
            const int p  = 2 - q;
            const int st = 1 << p;
            const float a0 = theta[l * 9 + q * 3 + 0];
            const float a1 = theta[l * 9 + q * 3 + 1];
            const float a2 = theta[l * 9 + q * 3 + 2];
            float sz, cz, sx, cx, sz2, cz2;
            sincosf(0.5f * a0, &sz,  &cz);
            sincosf(0.5f * a1, &sx,  &cx);
            sincosf(0.5f * a2, &sz2, &cz2);

            // RZ(a0)
#pragma unroll
            for (int k = 0; k < 8; ++k) {
                const float s = ((k >> p) & 1) ? sz : -sz;
                const float r0 = re[k] * cz - im[k] * s;
                const float i0 = re[k] * s  + im[k] * cz;
                re[k] = r0; im[k] = i0;
            }
            // RX(a1)
#pragma unroll
            for (int k = 0; k < 8; ++k) {
                if ((k >> p) & 1) continue;
                const int k1 = k + st;
                const float r0 =  cx * re[k]  + sx * im[k1];
                const float i0 =  cx * im[k]  - sx * re[k1];
                const float r1 =  sx * im[k]  + cx * re[k1];
                const float i1 = -sx * re[k]  + cx * im[k1];
                re[k] = r0; im[k] = i0; re[k1] = r1; im[k1] = i1;
            }
            // RZ(a2)
#pragma unroll
            for (int k = 0; k < 8; ++k) {
                const float s = ((k >> p) & 1) ? sz2 : -sz2;
                const float r0 = re[k] * cz2 - im[k] * s;
                const float i0 = re[k] * s   + im[k] * cz2;
                re[k] = r0; im[k] = i0;
            }
        }

        // CNOT(0,1), CNOT(1,2), CNOT(2,0)
#define SWP(a, b) { float tr = re[a]; re[a] = re[b]; re[b] = tr; \
                    float ti = im[a]; im[a] = im[b]; im[b] = ti; }
        SWP(4, 6); SWP(5, 7);
        SWP(2, 3); SWP(6, 7);
        SWP(1, 5); SWP(3, 7);
#undef SWP

#pragma unroll
        for (int r = 0; r < 8; ++r)
            sU[l * 64 + r * 8 + c] = make_float2(re[r], im[r]);
    }
    __syncthreads();

    // --- circuit eval at theta_j, j = tid (exact mod-64 angle reduction) ---
    {
        const int j = tid;
        const float w0 = (float)(M_PI / 32.0);   // 2*pi/64
        float c1, s1, c2, s2, c3, s3;
        sincosf(w0 * (float)j,              &s1, &c1);
        sincosf(w0 * (float)((2 * j) & 63), &s2, &c2);
        sincosf(w0 * (float)((3 * j) & 63), &s3, &c3);

        float wr[8], wi[8];
#pragma unroll
        for (int r = 0; r < 8; ++r) { const float2 u = sU[r * 8]; wr[r] = u.x; wi[r] = u.y; }

        rotF<4>(c1, s1, wr, wi);
        rotF<2>(c2, s2, wr, wi);
        rotF<1>(c3, s3, wr, wi);

        float xr[8], xi[8];
#pragma unroll
        for (int r = 0; r < 8; ++r) {
            float zr = 0.f, zi = 0.f;
#pragma unroll
            for (int cc = 0; cc < 8; ++cc) {
                const float2 u = sU[64 + r * 8 + cc];
                zr += u.x * wr[cc] - u.y * wi[cc];
                zi += u.x * wi[cc] + u.y * wr[cc];
            }
            xr[r] = zr; xi[r] = zi;
        }

        rotF<4>(c1, s1, xr, xi);
        rotF<2>(c2, s2, xr, xi);
        rotF<1>(c3, s3, xr, xi);

        float acc = 0.f;
#pragma unroll
        for (int r = 0; r < 8; ++r) {
            float zr = 0.f, zi = 0.f;
#pragma unroll
            for (int cc = 0; cc < 8; ++cc) {
                const float2 u = sU[128 + r * 8 + cc];
                zr += u.x * xr[cc] - u.y * xi[cc];
                zi += u.x * xi[cc] + u.y * xr[cc];
            }
            const float m = zr * zr + zi * zi;
            acc += (r < 4) ? m : -m;
        }
        sOut[j] = acc;
    }
    __syncthreads();

    // --- 64-point real DFT, k = 0..24 ---
    if (tid < 26) {
        if (tid == 25) {
            g_coef[50] = 0.f; g_coef[51] = 0.f;
        } else {
            const float w0 = (float)(M_PI / 32.0);
            float sa = 0.f, sb = 0.f;
            for (int j = 0; j < 64; ++j) {
                const int m = (tid * j) & 63;           // exact angle reduction
                float s, c;
                sincosf(w0 * (float)m, &s, &c);
                sa += sOut[j] * c;
                sb += sOut[j] * s;
            }
            const float sc = (tid == 0) ? (1.f / 64.f) : (2.f / 64.f);
            g_coef[2 * tid]     = sa * sc;
            g_coef[2 * tid + 1] = (tid == 0) ? 0.f : sb * sc;
        }
    }
}

// ---------------------------------------------------------------------------
// Main: 1 thread = 4 samples. Chebyshev recurrence over 25 harmonics,
// coefficients held in SGPRs via readfirstlane.
// ---------------------------------------------------------------------------
__device__ __forceinline__ float evalSeries(float tval,
                                            const float (&A)[26], const float (&Bv)[26])
{
    const float th = 1.5707963267948966f * tval;   // theta = pi*t/2
    float s1, c1;
    __sincosf(th, &s1, &c1);
    const float tc = 2.f * c1;
    float cp = 1.f, sp = 0.f;    // cos(0), sin(0)
    float cc = c1,  sc = s1;     // cos(1), sin(1)
    float acc = A[0] + A[1] * cc + Bv[1] * sc;
#pragma unroll
    for (int k = 2; k <= 25; ++k) {
        const float cn = tc * cc - cp;
        const float sn = tc * sc - sp;
        cp = cc; sp = sc; cc = cn; sc = sn;
        acc += A[k] * cn + Bv[k] * sn;
    }
    return acc;
}

__global__ __launch_bounds__(256) void qb_main(const float* __restrict__ t,
                                               float* __restrict__ out, int n)
{
    // Hoist the 52 coefficients into SGPRs (uniform across the wave).
    float A[26], Bv[26];
    const float4* cg = reinterpret_cast<const float4*>(g_coef);
#pragma unroll
    for (int q = 0; q < 13; ++q) {
        const float4 v = cg[q];
        A[2 * q]      = rfl(v.x);
        Bv[2 * q]     = rfl(v.y);
        A[2 * q + 1]  = rfl(v.z);
        Bv[2 * q + 1] = rfl(v.w);
    }

    const int base = (blockIdx.x * 256 + threadIdx.x) * 4;
    if (base + 3 < n) {
        const float4 tv = *reinterpret_cast<const float4*>(t + base);
        float4 ov;
        ov.x = evalSeries(tv.x, A, Bv);
        ov.y = evalSeries(tv.y, A, Bv);
        ov.z = evalSeries(tv.z, A, Bv);
        ov.w = evalSeries(tv.w, A, Bv);
        *reinterpret_cast<float4*>(out + base) = ov;
    } else {
        for (int i = 0; i < 4; ++i)
            if (base + i < n) out[base + i] = evalSeries(t[base + i], A, Bv);
    }
}

extern "C" void kernel_launch(void* const* d_in, const int* in_sizes, int n_in,
                              void* d_out, int out_size, void* d_ws, size_t ws_size,
                              hipStream_t stream)
{
    const float* t     = (const float*)d_in[0];
    const float* theta = (const float*)d_in[1];
    float* out         = (float*)d_out;
    const int n = in_sizes[0];

    qb_prep<<<1, 64, 0, stream>>>(theta);
    const int blocks = (n + 1023) / 1024;   // 4 samples per thread
    qb_main<<<blocks, 256, 0, stream>>>(t, out, n);
}

// Round 3
// 71.038 us; speedup vs baseline: 1.6083x; 1.1184x over previous
//
#include <hip/hip_runtime.h>
#include <math.h>

#ifndef M_PI
#define M_PI 3.14159265358979323846
#endif

// 25 harmonics (k=0..24) of out(theta), theta = pi*t/2:
// g_coef[2k] = a_k (cos), g_coef[2k+1] = b_k (sin). [50],[51] zeroed.
__device__ float g_coef[52];

__device__ __forceinline__ float rfl(float x)
{
    return __int_as_float(__builtin_amdgcn_readfirstlane(__float_as_int(x)));
}

// Real RY butterfly on bit with stride ST: (a,b) -> (c*a - s*b, s*a + c*b)
template <int ST>
__device__ __forceinline__ void rotF(float c, float s, float (&vr)[8], float (&vi)[8])
{
#pragma unroll
    for (int k = 0; k < 8; ++k) {
        if (k & ST) continue;
        const int k1 = k + ST;
        const float ar = vr[k],  ai = vi[k];
        const float br = vr[k1], bi = vi[k1];
        vr[k]  = c * ar - s * br;  vi[k]  = c * ai - s * bi;
        vr[k1] = s * ar + c * br;  vi[k1] = s * ai + c * bi;
    }
}

// ---------------------------------------------------------------------------
// Prep (1 block, 64 threads), all-fast-math trig:
//  1) threads 0..23 build the three 8x8 ansatz-layer matrices into LDS
//  2) every thread j evaluates the circuit at theta_j = 2*pi*j/64
//  3) threads 0..24 do the 64-point real DFT -> a_k, b_k (exact: deg 24 < 32)
// ---------------------------------------------------------------------------
__global__ void qb_prep(const float* __restrict__ theta)
{
    __shared__ float2 sU[192];   // [layer][row][col]
    __shared__ float  sOut[64];
    const int tid = threadIdx.x;

    if (tid < 24) {
        const int l = tid >> 3;   // layer
        const int c = tid & 7;    // column

        float re[8], im[8];
#pragma unroll
        for (int k = 0; k < 8; ++k) { re[k] = (k == c) ? 1.f : 0.f; im[k] = 0.f; }

#pragma unroll
        for (int q = 0; q < 3; ++q) {
            const int p  = 2 - q;
            const int st = 1 << p;
            const float a0 = theta[l * 9 + q * 3 + 0];
            const float a1 = theta[l * 9 + q * 3 + 1];
            const float a2 = theta[l * 9 + q * 3 + 2];
            float sz, cz, sx, cx, sz2, cz2;
            __sincosf(0.5f * a0, &sz,  &cz);
            __sincosf(0.5f * a1, &sx,  &cx);
            __sincosf(0.5f * a2, &sz2, &cz2);

            // RZ(a0)
#pragma unroll
            for (int k = 0; k < 8; ++k) {
                const float s = ((k >> p) & 1) ? sz : -sz;
                const float r0 = re[k] * cz - im[k] * s;
                const float i0 = re[k] * s  + im[k] * cz;
                re[k] = r0; im[k] = i0;
            }
            // RX(a1)
#pragma unroll
            for (int k = 0; k < 8; ++k) {
                if ((k >> p) & 1) continue;
                const int k1 = k + st;
                const float r0 =  cx * re[k]  + sx * im[k1];
                const float i0 =  cx * im[k]  - sx * re[k1];
                const float r1 =  sx * im[k]  + cx * re[k1];
                const float i1 = -sx * re[k]  + cx * im[k1];
                re[k] = r0; im[k] = i0; re[k1] = r1; im[k1] = i1;
            }
            // RZ(a2)
#pragma unroll
            for (int k = 0; k < 8; ++k) {
                const float s = ((k >> p) & 1) ? sz2 : -sz2;
                const float r0 = re[k] * cz2 - im[k] * s;
                const float i0 = re[k] * s   + im[k] * cz2;
                re[k] = r0; im[k] = i0;
            }
        }

        // CNOT(0,1), CNOT(1,2), CNOT(2,0)
#define SWP(a, b) { float tr = re[a]; re[a] = re[b]; re[b] = tr; \
                    float ti = im[a]; im[a] = im[b]; im[b] = ti; }
        SWP(4, 6); SWP(5, 7);
        SWP(2, 3); SWP(6, 7);
        SWP(1, 5); SWP(3, 7);
#undef SWP

#pragma unroll
        for (int r = 0; r < 8; ++r)
            sU[l * 64 + r * 8 + c] = make_float2(re[r], im[r]);
    }
    __syncthreads();

    // --- circuit eval at theta_j, j = tid ---
    {
        const int j = tid;
        const float w0 = (float)(M_PI / 32.0);   // 2*pi/64
        float c1, s1;
        __sincosf(w0 * (float)j, &s1, &c1);
        const float c2 = c1 * c1 - s1 * s1, s2 = 2.f * s1 * c1;      // 2*theta_j
        const float c3 = c2 * c1 - s2 * s1, s3 = s2 * c1 + c2 * s1;  // 3*theta_j

        float wr[8], wi[8];
#pragma unroll
        for (int r = 0; r < 8; ++r) { const float2 u = sU[r * 8]; wr[r] = u.x; wi[r] = u.y; }

        rotF<4>(c1, s1, wr, wi);
        rotF<2>(c2, s2, wr, wi);
        rotF<1>(c3, s3, wr, wi);

        float xr[8], xi[8];
#pragma unroll
        for (int r = 0; r < 8; ++r) {
            float zr = 0.f, zi = 0.f;
#pragma unroll
            for (int cc = 0; cc < 8; ++cc) {
                const float2 u = sU[64 + r * 8 + cc];
                zr += u.x * wr[cc] - u.y * wi[cc];
                zi += u.x * wi[cc] + u.y * wr[cc];
            }
            xr[r] = zr; xi[r] = zi;
        }

        rotF<4>(c1, s1, xr, xi);
        rotF<2>(c2, s2, xr, xi);
        rotF<1>(c3, s3, xr, xi);

        float acc = 0.f;
#pragma unroll
        for (int r = 0; r < 8; ++r) {
            float zr = 0.f, zi = 0.f;
#pragma unroll
            for (int cc = 0; cc < 8; ++cc) {
                const float2 u = sU[128 + r * 8 + cc];
                zr += u.x * xr[cc] - u.y * xi[cc];
                zi += u.x * xi[cc] + u.y * xr[cc];
            }
            const float m = zr * zr + zi * zi;
            acc += (r < 4) ? m : -m;
        }
        sOut[j] = acc;
    }
    __syncthreads();

    // --- 64-point real DFT, k = 0..24 (exact mod-64 angle reduction) ---
    if (tid < 26) {
        if (tid == 25) {
            g_coef[50] = 0.f; g_coef[51] = 0.f;
        } else {
            const float w0 = (float)(M_PI / 32.0);
            float sa = 0.f, sb = 0.f;
            for (int j = 0; j < 64; ++j) {
                const int m = (tid * j) & 63;
                float s, c;
                __sincosf(w0 * (float)m, &s, &c);
                sa += sOut[j] * c;
                sb += sOut[j] * s;
            }
            const float sc = (tid == 0) ? (1.f / 64.f) : (2.f / 64.f);
            g_coef[2 * tid]     = sa * sc;
            g_coef[2 * tid + 1] = (tid == 0) ? 0.f : sb * sc;
        }
    }
}

// ---------------------------------------------------------------------------
// Main: 1 thread = 4 samples. Chebyshev recurrence over 25 harmonics,
// coefficients held in SGPRs via readfirstlane.
// ---------------------------------------------------------------------------
__device__ __forceinline__ float evalSeries(float tval,
                                            const float (&A)[26], const float (&Bv)[26])
{
    const float th = 1.5707963267948966f * tval;   // theta = pi*t/2
    float s1, c1;
    __sincosf(th, &s1, &c1);
    const float tc = 2.f * c1;
    float cp = 1.f, sp = 0.f;    // cos(0), sin(0)
    float cc = c1,  sc = s1;     // cos(1), sin(1)
    float acc = A[0] + A[1] * cc + Bv[1] * sc;
#pragma unroll
    for (int k = 2; k <= 25; ++k) {
        const float cn = tc * cc - cp;
        const float sn = tc * sc - sp;
        cp = cc; sp = sc; cc = cn; sc = sn;
        acc += A[k] * cn + Bv[k] * sn;
    }
    return acc;
}

__global__ __launch_bounds__(256) void qb_main(const float* __restrict__ t,
                                               float* __restrict__ out, int n)
{
    // Hoist the 52 coefficients into SGPRs (uniform across the wave).
    float A[26], Bv[26];
    const float4* cg = reinterpret_cast<const float4*>(g_coef);
#pragma unroll
    for (int q = 0; q < 13; ++q) {
        const float4 v = cg[q];
        A[2 * q]      = rfl(v.x);
        Bv[2 * q]     = rfl(v.y);
        A[2 * q + 1]  = rfl(v.z);
        Bv[2 * q + 1] = rfl(v.w);
    }

    const int base = (blockIdx.x * 256 + threadIdx.x) * 4;
    if (base + 3 < n) {
        const float4 tv = *reinterpret_cast<const float4*>(t + base);
        float4 ov;
        ov.x = evalSeries(tv.x, A, Bv);
        ov.y = evalSeries(tv.y, A, Bv);
        ov.z = evalSeries(tv.z, A, Bv);
        ov.w = evalSeries(tv.w, A, Bv);
        *reinterpret_cast<float4*>(out + base) = ov;
    } else {
        for (int i = 0; i < 4; ++i)
            if (base + i < n) out[base + i] = evalSeries(t[base + i], A, Bv);
    }
}

extern "C" void kernel_launch(void* const* d_in, const int* in_sizes, int n_in,
                              void* d_out, int out_size, void* d_ws, size_t ws_size,
                              hipStream_t stream)
{
    const float* t     = (const float*)d_in[0];
    const float* theta = (const float*)d_in[1];
    float* out         = (float*)d_out;
    const int n = in_sizes[0];

    qb_prep<<<1, 64, 0, stream>>>(theta);
    const int blocks = (n + 1023) / 1024;   // 4 samples per thread
    qb_main<<<blocks, 256, 0, stream>>>(t, out, n);
}